// Round 7
// baseline (417.401 us; speedup 1.0000x reference)
//
#include <hip/hip_runtime.h>

// MHA forward: B=2, S=2048, D=1024, H=16, dk=64.
// Pipeline: cvt x,W -> bf16; Q,K GEMMs + V GEMM (transposed out) -> flash attn -> O GEMM.
// ws layout (bf16 elems): Qb[4M] Kb[4M] Vt[4M] Xb/Ctx[4M] (+Wb[4x1M] if ws >= 40MB).

#define D_MODEL 1024
#define SEQ     2048
#define NHEAD   16
#define DKH     64
#define MROWS   4096   // B*S

typedef __attribute__((ext_vector_type(8))) short bf16x8;
typedef __attribute__((ext_vector_type(4))) float f32x4;

__device__ __forceinline__ unsigned short f2bf(float f) {
    union { float f; unsigned u; } v; v.f = f;
    unsigned r = (v.u + 0x7fffu + ((v.u >> 16) & 1u)) >> 16;   // RNE
    return (unsigned short)r;
}
__device__ __forceinline__ unsigned short f2bf_fast(float f) {  // round-half-up (P in [0,1])
    union { float f; unsigned u; } v; v.f = f;
    return (unsigned short)((v.u + 0x8000u) >> 16);
}
__device__ __forceinline__ unsigned long long pack4(float4 v) {
    return (unsigned long long)f2bf(v.x)
         | ((unsigned long long)f2bf(v.y) << 16)
         | ((unsigned long long)f2bf(v.z) << 32)
         | ((unsigned long long)f2bf(v.w) << 48);
}

// XOR swizzle: spreads 128B-stride rows across banks; preserves 16B alignment.
__device__ __forceinline__ int swz(int row, int byte) { return byte ^ ((row & 7) << 4); }

// DPP 16-lane butterfly reduce (reduce group = one DPP row of 16 lanes).
#define DPP_F(x, ctrl) __builtin_bit_cast(float, __builtin_amdgcn_mov_dpp(__builtin_bit_cast(int, (x)), (ctrl), 0xf, 0xf, true))
__device__ __forceinline__ float redmax16(float x) {
    x = fmaxf(x, DPP_F(x, 0xB1));
    x = fmaxf(x, DPP_F(x, 0x4E));
    x = fmaxf(x, DPP_F(x, 0x141));
    x = fmaxf(x, DPP_F(x, 0x140));
    return x;
}
__device__ __forceinline__ float redsum16(float x) {
    x += DPP_F(x, 0xB1);
    x += DPP_F(x, 0x4E);
    x += DPP_F(x, 0x141);
    x += DPP_F(x, 0x140);
    return x;
}

// ---------------------------------------------------------------------------
// fp32 -> bf16 bulk convert (n4 = element count / 4)
// ---------------------------------------------------------------------------
__global__ __launch_bounds__(256) void cvt_bf16(const float* __restrict__ src,
                                                unsigned short* __restrict__ dst, int n4)
{
    int i = blockIdx.x * 256 + threadIdx.x;
    if (i < n4) {
        float4 v = reinterpret_cast<const float4*>(src)[i];
        reinterpret_cast<unsigned long long*>(dst)[i] = pack4(v);
    }
}

// ---------------------------------------------------------------------------
// NT GEMM: C[128x128 tile] = (A[M,K] @ W[N,K]^T + bias) * oscale. K = 1024.
// A always bf16. W bf16 or fp32 (fallback). Register-prefetch pipeline.
// OUT_T: store transposed Ct[n][m] (stride MROWS) -- used for V.
// ---------------------------------------------------------------------------
template<bool W_BF16, bool OUT_BF16, bool OUT_T>
__global__ __launch_bounds__(256) void gemm_nt(const unsigned short* __restrict__ Ap,
                                               const void* __restrict__ Wp,
                                               const float* __restrict__ bias,
                                               void* __restrict__ Cp, float oscale)
{
    __shared__ __align__(16) unsigned char lds[32768];  // A tile 16K + W tile 16K
    const int tid = threadIdx.x;
    const int w = tid >> 6, l = tid & 63;
    const int m0 = blockIdx.y * 128, n0 = blockIdx.x * 128;
    const int wm = (w >> 1) * 64, wn = (w & 1) * 64;
    const int lr = l & 15, lk = l >> 4;

    f32x4 acc[4][4] = {};
    int4 ra[4], rwb[4];
    float4 rwf[8];

    auto loadA = [&](int k0) {
        #pragma unroll
        for (int i = 0; i < 4; i++) {
            int c = tid + i * 256;
            int row = c >> 3, col8 = c & 7;
            ra[i] = *reinterpret_cast<const int4*>(Ap + (size_t)(m0 + row) * D_MODEL + k0 + col8 * 8);
        }
    };
    auto loadW = [&](int k0) {
        if constexpr (W_BF16) {
            const unsigned short* W = (const unsigned short*)Wp;
            #pragma unroll
            for (int i = 0; i < 4; i++) {
                int c = tid + i * 256;
                int row = c >> 3, col8 = c & 7;
                rwb[i] = *reinterpret_cast<const int4*>(W + (size_t)(n0 + row) * D_MODEL + k0 + col8 * 8);
            }
        } else {
            const float* W = (const float*)Wp;
            #pragma unroll
            for (int i = 0; i < 8; i++) {
                int c = tid + i * 256;
                int row = c >> 4, col4 = c & 15;
                rwf[i] = *reinterpret_cast<const float4*>(W + (size_t)(n0 + row) * D_MODEL + k0 + col4 * 4);
            }
        }
    };
    auto storeT = [&]() {
        #pragma unroll
        for (int i = 0; i < 4; i++) {
            int c = tid + i * 256;
            int row = c >> 3, col8 = c & 7;
            *reinterpret_cast<int4*>(lds + swz(row, row * 128 + col8 * 16)) = ra[i];
        }
        if constexpr (W_BF16) {
            #pragma unroll
            for (int i = 0; i < 4; i++) {
                int c = tid + i * 256;
                int row = c >> 3, col8 = c & 7;
                *reinterpret_cast<int4*>(lds + 16384 + swz(row, row * 128 + col8 * 16)) = rwb[i];
            }
        } else {
            #pragma unroll
            for (int i = 0; i < 8; i++) {
                int c = tid + i * 256;
                int row = c >> 4, col4 = c & 15;
                *reinterpret_cast<unsigned long long*>(lds + 16384 + swz(row, row * 128 + col4 * 8)) = pack4(rwf[i]);
            }
        }
    };

    loadA(0); loadW(0);
    for (int k0 = 0; k0 < D_MODEL; k0 += 64) {
        __syncthreads();
        storeT();
        if (k0 + 64 < D_MODEL) { loadA(k0 + 64); loadW(k0 + 64); }
        __syncthreads();
        #pragma unroll
        for (int ks = 0; ks < 2; ks++) {
            bf16x8 af[4], bfr[4];
            #pragma unroll
            for (int rt = 0; rt < 4; rt++) {
                int row = wm + rt * 16 + lr;
                af[rt] = *reinterpret_cast<const bf16x8*>(lds + swz(row, row * 128 + ks * 64 + lk * 16));
            }
            #pragma unroll
            for (int ct = 0; ct < 4; ct++) {
                int row = wn + ct * 16 + lr;
                bfr[ct] = *reinterpret_cast<const bf16x8*>(lds + 16384 + swz(row, row * 128 + ks * 64 + lk * 16));
            }
            #pragma unroll
            for (int rt = 0; rt < 4; rt++)
                #pragma unroll
                for (int ct = 0; ct < 4; ct++)
                    acc[rt][ct] = __builtin_amdgcn_mfma_f32_16x16x32_bf16(af[rt], bfr[ct], acc[rt][ct], 0, 0, 0);
        }
    }
    #pragma unroll
    for (int ct = 0; ct < 4; ct++) {
        int n = n0 + wn + ct * 16 + lr;
        float bv = bias[n];
        #pragma unroll
        for (int rt = 0; rt < 4; rt++) {
            #pragma unroll
            for (int j = 0; j < 4; j++) {
                int m = m0 + wm + rt * 16 + lk * 4 + j;
                float v = (acc[rt][ct][j] + bv) * oscale;
                if constexpr (OUT_T)
                    ((unsigned short*)Cp)[(size_t)n * MROWS + m] = f2bf(v);
                else if constexpr (OUT_BF16)
                    ((unsigned short*)Cp)[(size_t)m * D_MODEL + n] = f2bf(v);
                else
                    ((float*)Cp)[(size_t)m * D_MODEL + n] = v;
            }
        }
    }
}

// ---------------------------------------------------------------------------
// Causal flash attention -- wave-independent, barrier-free.
// Grid: (S/64, B*H), 256 threads = 4 waves; wave w owns q-rows gx*64+w*16 .. +15.
// MFMA B-fragments (K rows, V^T rows) loaded DIRECTLY from global (L2/L3-resident;
// 16B/lane, 64B-granule coalesced). Only per-wave P goes through LDS.
// Q pre-scaled by 0.125*log2(e) in the Q-GEMM.
// ---------------------------------------------------------------------------
__global__ __launch_bounds__(256, 4) void attn_fwd(const unsigned short* __restrict__ Qb,
                                                   const unsigned short* __restrict__ Kb,
                                                   const unsigned short* __restrict__ Vt,
                                                   unsigned short* __restrict__ Ctx)
{
    __shared__ __align__(16) unsigned char plds[4][16 * 144]; // per-wave P [16][64+8pad]

    const int tid = threadIdx.x, w = tid >> 6, l = tid & 63;
    const int lr = l & 15, lk = l >> 4;
    const int gx = (int)gridDim.x - 1 - (int)blockIdx.x;          // big blocks first
    const int b = blockIdx.y >> 4, h = blockIdx.y & 15;
    const size_t headoff = (size_t)b * SEQ * D_MODEL + (size_t)h * DKH;   // Q/K/Ctx
    const size_t vtoff   = (size_t)h * DKH * MROWS + (size_t)b * SEQ;     // Vt[h*64+d][b*2048+kv]
    const int qrow = gx * 64 + w * 16;

    // Q fragments (A-operand: lane(lr,lk) holds Q[qrow+lr][lk*8..+8]), pre-scaled
    bf16x8 aq[2];
    #pragma unroll
    for (int ks = 0; ks < 2; ks++)
        aq[ks] = *reinterpret_cast<const bf16x8*>(
            Qb + headoff + (size_t)(qrow + lr) * D_MODEL + ks * 32 + lk * 8);

    // per-lane base pointers for B-fragment loads
    const unsigned short* kp = Kb + headoff + (size_t)lr * D_MODEL + lk * 8;
    const unsigned short* vp = Vt + vtoff + (size_t)lr * MROWS + lk * 8;

    f32x4 o[4] = {};
    float m_i[4], l_i[4];
    #pragma unroll
    for (int j = 0; j < 4; j++) { m_i[j] = -INFINITY; l_i[j] = 0.f; }

    const int ntiles = gx + 1;
    for (int t = 0; t < ntiles; t++) {
        const int kv0 = t * 64;

        // ---- S = Q K^T : B-frags straight from global K ----
        bf16x8 bk[4][2];
        #pragma unroll
        for (int ct = 0; ct < 4; ct++)
            #pragma unroll
            for (int ks = 0; ks < 2; ks++)
                bk[ct][ks] = *reinterpret_cast<const bf16x8*>(kp + (size_t)(kv0 + ct * 16) * D_MODEL + ks * 32);
        f32x4 s[4];
        #pragma unroll
        for (int ct = 0; ct < 4; ct++) {
            f32x4 a = {0.f, 0.f, 0.f, 0.f};
            a = __builtin_amdgcn_mfma_f32_16x16x32_bf16(aq[0], bk[ct][0], a, 0, 0, 0);
            a = __builtin_amdgcn_mfma_f32_16x16x32_bf16(aq[1], bk[ct][1], a, 0, 0, 0);
            s[ct] = a;
        }

        // ---- causal mask + online softmax (DPP reduces; raw v_exp_f32) ----
        const bool needmask = (kv0 + 63) > qrow;
        float mx[4] = {-INFINITY, -INFINITY, -INFINITY, -INFINITY};
        #pragma unroll
        for (int ct = 0; ct < 4; ct++) {
            #pragma unroll
            for (int j = 0; j < 4; j++) {
                float v = s[ct][j];
                if (needmask) {
                    int row = qrow + lk * 4 + j;
                    int col = kv0 + ct * 16 + lr;
                    if (col > row) v = -INFINITY;
                }
                s[ct][j] = v;
                mx[j] = fmaxf(mx[j], v);
            }
        }
        #pragma unroll
        for (int j = 0; j < 4; j++) {
            mx[j] = redmax16(mx[j]);
            float mnew = fmaxf(m_i[j], mx[j]);
            float corr = __builtin_amdgcn_exp2f(m_i[j] - mnew);
            m_i[j] = mnew;
            l_i[j] *= corr;
            #pragma unroll
            for (int dt = 0; dt < 4; dt++) o[dt][j] *= corr;
        }
        float rs[4] = {0.f, 0.f, 0.f, 0.f};
        #pragma unroll
        for (int ct = 0; ct < 4; ct++) {
            #pragma unroll
            for (int j = 0; j < 4; j++) {
                float p = __builtin_amdgcn_exp2f(s[ct][j] - m_i[j]);
                rs[j] += p;
                *reinterpret_cast<unsigned short*>(&plds[w][0] + (lk * 4 + j) * 144 + (ct * 16 + lr) * 2) = f2bf_fast(p);
            }
        }
        #pragma unroll
        for (int j = 0; j < 4; j++) l_i[j] += redsum16(rs[j]);

        __threadfence_block();   // per-wave P write->read ordering

        // ---- O += P V : P A-frag from LDS, V B-frags straight from global Vt ----
        bf16x8 pa[2];
        #pragma unroll
        for (int ks = 0; ks < 2; ks++)
            pa[ks] = *reinterpret_cast<const bf16x8*>(&plds[w][0] + lr * 144 + ks * 64 + lk * 16);
        #pragma unroll
        for (int dt = 0; dt < 4; dt++) {
            bf16x8 v0 = *reinterpret_cast<const bf16x8*>(vp + (size_t)(dt * 16) * MROWS + kv0);
            bf16x8 v1 = *reinterpret_cast<const bf16x8*>(vp + (size_t)(dt * 16) * MROWS + kv0 + 32);
            o[dt] = __builtin_amdgcn_mfma_f32_16x16x32_bf16(pa[0], v0, o[dt], 0, 0, 0);
            o[dt] = __builtin_amdgcn_mfma_f32_16x16x32_bf16(pa[1], v1, o[dt], 0, 0, 0);
        }
    }

    // ---- epilogue: normalize + store ctx (bf16) ----
    #pragma unroll
    for (int j = 0; j < 4; j++) {
        float inv = 1.0f / l_i[j];
        int row = qrow + lk * 4 + j;
        #pragma unroll
        for (int dt = 0; dt < 4; dt++)
            Ctx[headoff + (size_t)row * D_MODEL + dt * 16 + lr] = f2bf(o[dt][j] * inv);
    }
}

extern "C" void kernel_launch(void* const* d_in, const int* in_sizes, int n_in,
                              void* d_out, int out_size, void* d_ws, size_t ws_size,
                              hipStream_t stream)
{
    const float* x   = (const float*)d_in[0];
    const float* w_q = (const float*)d_in[2];
    const float* b_q = (const float*)d_in[3];
    const float* w_k = (const float*)d_in[4];
    const float* b_k = (const float*)d_in[5];
    const float* w_v = (const float*)d_in[6];
    const float* b_v = (const float*)d_in[7];
    const float* w_o = (const float*)d_in[8];
    const float* b_o = (const float*)d_in[9];

    const size_t SEG = (size_t)MROWS * D_MODEL;        // 4M elems
    const size_t WSEG = (size_t)D_MODEL * D_MODEL;     // 1M elems
    unsigned short* Qb  = (unsigned short*)d_ws;
    unsigned short* Kb  = Qb + SEG;
    unsigned short* Vt  = Kb + SEG;                    // [1024][4096] (transposed)
    unsigned short* Xb  = Vt + SEG;                    // x bf16; later reused as Ctx
    unsigned short* Ctx = Xb;                          // alias: attn overwrites after x consumed
    unsigned short* Wqb = Xb + SEG;
    unsigned short* Wkb = Wqb + WSEG;
    unsigned short* Wvb = Wkb + WSEG;
    unsigned short* Wob = Wvb + WSEG;
    const bool fullws = ws_size >= (4 * SEG + 4 * WSEG) * 2;   // 40 MB

    const float QSC = 0.125f * 1.44269504088896f;  // 1/sqrt(dk) * log2(e), folded into Q

    dim3 blk(256);
    dim3 ggrid(D_MODEL / 128, MROWS / 128);        // (8, 32)
    dim3 agrid(SEQ / 64, 32);                      // (32, 32)

    hipLaunchKernelGGL(cvt_bf16, dim3(4096), blk, 0, stream, x, Xb, (int)(SEG / 4));
    if (fullws) {
        hipLaunchKernelGGL(cvt_bf16, dim3(1024), blk, 0, stream, w_q, Wqb, (int)(WSEG / 4));
        hipLaunchKernelGGL(cvt_bf16, dim3(1024), blk, 0, stream, w_k, Wkb, (int)(WSEG / 4));
        hipLaunchKernelGGL(cvt_bf16, dim3(1024), blk, 0, stream, w_v, Wvb, (int)(WSEG / 4));
        hipLaunchKernelGGL(cvt_bf16, dim3(1024), blk, 0, stream, w_o, Wob, (int)(WSEG / 4));
        hipLaunchKernelGGL((gemm_nt<true, true, false>), ggrid, blk, 0, stream, Xb, (const void*)Wqb, b_q, (void*)Qb, QSC);
        hipLaunchKernelGGL((gemm_nt<true, true, false>), ggrid, blk, 0, stream, Xb, (const void*)Wkb, b_k, (void*)Kb, 1.0f);
        hipLaunchKernelGGL((gemm_nt<true, true, true >), ggrid, blk, 0, stream, Xb, (const void*)Wvb, b_v, (void*)Vt, 1.0f);
        hipLaunchKernelGGL(attn_fwd, agrid, blk, 0, stream, Qb, Kb, Vt, Ctx);
        hipLaunchKernelGGL((gemm_nt<true, false, false>), ggrid, blk, 0, stream, Ctx, (const void*)Wob, b_o, d_out, 1.0f);
    } else {
        hipLaunchKernelGGL((gemm_nt<false, true, false>), ggrid, blk, 0, stream, Xb, (const void*)w_q, b_q, (void*)Qb, QSC);
        hipLaunchKernelGGL((gemm_nt<false, true, false>), ggrid, blk, 0, stream, Xb, (const void*)w_k, b_k, (void*)Kb, 1.0f);
        hipLaunchKernelGGL((gemm_nt<false, true, true >), ggrid, blk, 0, stream, Xb, (const void*)w_v, b_v, (void*)Vt, 1.0f);
        hipLaunchKernelGGL(attn_fwd, agrid, blk, 0, stream, Qb, Kb, Vt, Ctx);
        hipLaunchKernelGGL((gemm_nt<false, false, false>), ggrid, blk, 0, stream, Ctx, (const void*)w_o, b_o, d_out, 1.0f);
    }
}

// Round 8
// 327.419 us; speedup vs baseline: 1.2748x; 1.2748x over previous
//
#include <hip/hip_runtime.h>

// MHA forward: B=2, S=2048, D=1024, H=16, dk=64.
// Pipeline: cvt x,W -> bf16; fused QKV GEMM (V transposed out) -> flash attn -> O GEMM.
// ws layout (bf16 elems): Qb[4M] Kb[4M] Vt[4M] Xb/Ctx[4M] (+Wb[4x1M] if ws >= 40MB).
// KEY fix this round: issue global prefetch AFTER the second barrier, never before it
// (the compiler's pre-barrier s_waitcnt vmcnt(0) otherwise drains the prefetch in-chain).

#define D_MODEL 1024
#define SEQ     2048
#define NHEAD   16
#define DKH     64
#define MROWS   4096   // B*S

typedef __attribute__((ext_vector_type(8))) short bf16x8;
typedef __attribute__((ext_vector_type(4))) float f32x4;

__device__ __forceinline__ unsigned short f2bf(float f) {
    union { float f; unsigned u; } v; v.f = f;
    unsigned r = (v.u + 0x7fffu + ((v.u >> 16) & 1u)) >> 16;   // RNE
    return (unsigned short)r;
}
__device__ __forceinline__ unsigned short f2bf_fast(float f) {  // round-half-up (P in [0,1])
    union { float f; unsigned u; } v; v.f = f;
    return (unsigned short)((v.u + 0x8000u) >> 16);
}
__device__ __forceinline__ unsigned long long pack4(float4 v) {
    return (unsigned long long)f2bf(v.x)
         | ((unsigned long long)f2bf(v.y) << 16)
         | ((unsigned long long)f2bf(v.z) << 32)
         | ((unsigned long long)f2bf(v.w) << 48);
}

// XOR swizzle: spreads 128B-stride rows across banks; preserves 16B alignment.
__device__ __forceinline__ int swz(int row, int byte) { return byte ^ ((row & 7) << 4); }

// DPP 16-lane butterfly reduce (reduce group = one DPP row of 16 lanes).
#define DPP_F(x, ctrl) __builtin_bit_cast(float, __builtin_amdgcn_mov_dpp(__builtin_bit_cast(int, (x)), (ctrl), 0xf, 0xf, true))
__device__ __forceinline__ float redmax16(float x) {
    x = fmaxf(x, DPP_F(x, 0xB1));
    x = fmaxf(x, DPP_F(x, 0x4E));
    x = fmaxf(x, DPP_F(x, 0x141));
    x = fmaxf(x, DPP_F(x, 0x140));
    return x;
}
__device__ __forceinline__ float redsum16(float x) {
    x += DPP_F(x, 0xB1);
    x += DPP_F(x, 0x4E);
    x += DPP_F(x, 0x141);
    x += DPP_F(x, 0x140);
    return x;
}

// ---------------------------------------------------------------------------
// fp32 -> bf16 bulk converts
// ---------------------------------------------------------------------------
__global__ __launch_bounds__(256) void cvt_bf16(const float* __restrict__ src,
                                                unsigned short* __restrict__ dst, int n4)
{
    int i = blockIdx.x * 256 + threadIdx.x;
    if (i < n4) {
        float4 v = reinterpret_cast<const float4*>(src)[i];
        reinterpret_cast<unsigned long long*>(dst)[i] = pack4(v);
    }
}
__global__ __launch_bounds__(256) void cvt_w4(const float* s0, const float* s1,
                                              const float* s2, const float* s3,
                                              unsigned short* d0, unsigned short* d1,
                                              unsigned short* d2, unsigned short* d3, int n4)
{
    const float* s = (blockIdx.z == 0) ? s0 : (blockIdx.z == 1) ? s1 : (blockIdx.z == 2) ? s2 : s3;
    unsigned short* d = (blockIdx.z == 0) ? d0 : (blockIdx.z == 1) ? d1 : (blockIdx.z == 2) ? d2 : d3;
    int i = blockIdx.x * 256 + threadIdx.x;
    if (i < n4) {
        float4 v = reinterpret_cast<const float4*>(s)[i];
        reinterpret_cast<unsigned long long*>(d)[i] = pack4(v);
    }
}

// ---------------------------------------------------------------------------
// Shared GEMM body: C[128x128 tile] = (A @ W^T + bias) * oscale, K = 1024.
// Correct pipeline: sync; storeLDS; sync; issue next loads; compute.
// ---------------------------------------------------------------------------
template<bool W_BF16>
__device__ __forceinline__ void gemm_body(const unsigned short* __restrict__ Ap,
                                          const void* __restrict__ Wp,
                                          const float* __restrict__ bias,
                                          void* __restrict__ Cp, float oscale,
                                          bool outT, bool outBF16,
                                          int m0, int n0, unsigned char* lds)
{
    const int tid = threadIdx.x;
    const int w = tid >> 6, l = tid & 63;
    const int wm = (w >> 1) * 64, wn = (w & 1) * 64;
    const int lr = l & 15, lk = l >> 4;

    f32x4 acc[4][4] = {};
    int4 ra[4], rwb[4];
    float4 rwf[8];

    auto loadA = [&](int k0) {
        #pragma unroll
        for (int i = 0; i < 4; i++) {
            int c = tid + i * 256;
            int row = c >> 3, col8 = c & 7;
            ra[i] = *reinterpret_cast<const int4*>(Ap + (size_t)(m0 + row) * D_MODEL + k0 + col8 * 8);
        }
    };
    auto loadW = [&](int k0) {
        if constexpr (W_BF16) {
            const unsigned short* W = (const unsigned short*)Wp;
            #pragma unroll
            for (int i = 0; i < 4; i++) {
                int c = tid + i * 256;
                int row = c >> 3, col8 = c & 7;
                rwb[i] = *reinterpret_cast<const int4*>(W + (size_t)(n0 + row) * D_MODEL + k0 + col8 * 8);
            }
        } else {
            const float* W = (const float*)Wp;
            #pragma unroll
            for (int i = 0; i < 8; i++) {
                int c = tid + i * 256;
                int row = c >> 4, col4 = c & 15;
                rwf[i] = *reinterpret_cast<const float4*>(W + (size_t)(n0 + row) * D_MODEL + k0 + col4 * 4);
            }
        }
    };
    auto storeT = [&]() {
        #pragma unroll
        for (int i = 0; i < 4; i++) {
            int c = tid + i * 256;
            int row = c >> 3, col8 = c & 7;
            *reinterpret_cast<int4*>(lds + swz(row, row * 128 + col8 * 16)) = ra[i];
        }
        if constexpr (W_BF16) {
            #pragma unroll
            for (int i = 0; i < 4; i++) {
                int c = tid + i * 256;
                int row = c >> 3, col8 = c & 7;
                *reinterpret_cast<int4*>(lds + 16384 + swz(row, row * 128 + col8 * 16)) = rwb[i];
            }
        } else {
            #pragma unroll
            for (int i = 0; i < 8; i++) {
                int c = tid + i * 256;
                int row = c >> 4, col4 = c & 15;
                *reinterpret_cast<unsigned long long*>(lds + 16384 + swz(row, row * 128 + col4 * 8)) = pack4(rwf[i]);
            }
        }
    };

    loadA(0); loadW(0);
    for (int k0 = 0; k0 < D_MODEL; k0 += 64) {
        __syncthreads();                    // waves done reading previous tile
        storeT();
        __syncthreads();                    // tile visible (drains LDS writes only)
        if (k0 + 64 < D_MODEL) { loadA(k0 + 64); loadW(k0 + 64); }  // AFTER barrier: latency hides under compute
        #pragma unroll
        for (int ks = 0; ks < 2; ks++) {
            bf16x8 af[4], bfr[4];
            #pragma unroll
            for (int rt = 0; rt < 4; rt++) {
                int row = wm + rt * 16 + lr;
                af[rt] = *reinterpret_cast<const bf16x8*>(lds + swz(row, row * 128 + ks * 64 + lk * 16));
            }
            #pragma unroll
            for (int ct = 0; ct < 4; ct++) {
                int row = wn + ct * 16 + lr;
                bfr[ct] = *reinterpret_cast<const bf16x8*>(lds + 16384 + swz(row, row * 128 + ks * 64 + lk * 16));
            }
            #pragma unroll
            for (int rt = 0; rt < 4; rt++)
                #pragma unroll
                for (int ct = 0; ct < 4; ct++)
                    acc[rt][ct] = __builtin_amdgcn_mfma_f32_16x16x32_bf16(af[rt], bfr[ct], acc[rt][ct], 0, 0, 0);
        }
    }
    #pragma unroll
    for (int ct = 0; ct < 4; ct++) {
        int n = n0 + wn + ct * 16 + lr;
        float bv = bias[n];
        #pragma unroll
        for (int rt = 0; rt < 4; rt++) {
            #pragma unroll
            for (int j = 0; j < 4; j++) {
                int m = m0 + wm + rt * 16 + lk * 4 + j;
                float v = (acc[rt][ct][j] + bv) * oscale;
                if (outT)
                    ((unsigned short*)Cp)[(size_t)n * MROWS + m] = f2bf(v);
                else if (outBF16)
                    ((unsigned short*)Cp)[(size_t)m * D_MODEL + n] = f2bf(v);
                else
                    ((float*)Cp)[(size_t)m * D_MODEL + n] = v;
            }
        }
    }
}

// Fused QKV GEMM: blockIdx.z in {0,1,2} -> (Q, K, V^T). 3x blocks/CU vs serial.
template<bool W_BF16>
__global__ __launch_bounds__(256) void gemm_qkv(const unsigned short* __restrict__ Xb,
                                                const void* W0, const void* W1, const void* W2,
                                                const float* b0, const float* b1, const float* b2,
                                                void* C0, void* C1, void* C2, float qsc)
{
    __shared__ __align__(16) unsigned char lds[32768];
    const int z = blockIdx.z;
    const void* W = (z == 0) ? W0 : (z == 1) ? W1 : W2;
    const float* bias = (z == 0) ? b0 : (z == 1) ? b1 : b2;
    void* C = (z == 0) ? C0 : (z == 1) ? C1 : C2;
    gemm_body<W_BF16>(Xb, W, bias, C, (z == 0) ? qsc : 1.0f, z == 2, true,
                      blockIdx.y * 128, blockIdx.x * 128, lds);
}

// Single GEMM (output projection): fp32 out.
template<bool W_BF16>
__global__ __launch_bounds__(256) void gemm_o(const unsigned short* __restrict__ Ap,
                                              const void* __restrict__ Wp,
                                              const float* __restrict__ bias,
                                              void* __restrict__ Cp)
{
    __shared__ __align__(16) unsigned char lds[32768];
    gemm_body<W_BF16>(Ap, Wp, bias, Cp, 1.0f, false, false,
                      blockIdx.y * 128, blockIdx.x * 128, lds);
}

// ---------------------------------------------------------------------------
// Causal flash attention. Grid: (S/64, B*H). 4 waves; wave owns 16 Q-rows.
// KV tile = 64 staged via regs -> swizzled LDS; prefetch issued AFTER barrier 2
// so its latency hides under this tile's compute instead of being drained.
// ---------------------------------------------------------------------------
__global__ __launch_bounds__(256) void attn_fwd(const unsigned short* __restrict__ Qb,
                                                const unsigned short* __restrict__ Kb,
                                                const unsigned short* __restrict__ Vt,
                                                unsigned short* __restrict__ Ctx)
{
    __shared__ __align__(16) unsigned char klds[8192];        // K tile [64][64] bf16
    __shared__ __align__(16) unsigned char vlds[8192];        // V^T tile [64][64] bf16
    __shared__ __align__(16) unsigned char plds[4][16 * 144]; // per-wave P [16][64+8pad]

    const int tid = threadIdx.x, w = tid >> 6, l = tid & 63;
    const int lr = l & 15, lk = l >> 4;
    const int q0 = ((int)gridDim.x - 1 - (int)blockIdx.x) * 64;   // big blocks first
    const int b = blockIdx.y >> 4, h = blockIdx.y & 15;
    const size_t headoff = (size_t)b * SEQ * D_MODEL + (size_t)h * DKH;   // Q/K/Ctx
    const size_t vtoff   = (size_t)h * DKH * MROWS + (size_t)b * SEQ;     // Vt[h*64+d][b*2048+kv]
    const int qrow = q0 + w * 16;

    // Q fragments (held for the whole kernel; Q pre-scaled by 0.125*log2e)
    bf16x8 aq[2];
    #pragma unroll
    for (int ks = 0; ks < 2; ks++)
        aq[ks] = *reinterpret_cast<const bf16x8*>(
            Qb + headoff + (size_t)(qrow + lr) * D_MODEL + ks * 32 + lk * 8);

    f32x4 o[4] = {};
    float m_i[4], l_i[4];
    #pragma unroll
    for (int j = 0; j < 4; j++) { m_i[j] = -INFINITY; l_i[j] = 0.f; }

    const int row_s = tid >> 3, col8 = tid & 7;
    auto load = [&](int t, int4* kr, int4* vr) {
        const int kv0 = t * 64;
        #pragma unroll
        for (int i = 0; i < 2; i++) {
            int row = row_s + i * 32;
            kr[i] = *reinterpret_cast<const int4*>(Kb + headoff + (size_t)(kv0 + row) * D_MODEL + col8 * 8);
            vr[i] = *reinterpret_cast<const int4*>(Vt + vtoff + (size_t)row * MROWS + kv0 + col8 * 8);
        }
    };
    auto store = [&](const int4* kr, const int4* vr) {
        #pragma unroll
        for (int i = 0; i < 2; i++) {
            int row = row_s + i * 32;
            *reinterpret_cast<int4*>(klds + swz(row, row * 128 + col8 * 16)) = kr[i];
            *reinterpret_cast<int4*>(vlds + swz(row, row * 128 + col8 * 16)) = vr[i];
        }
    };

    const int ntiles = q0 / 64 + 1;
    int4 kr[2], vr[2];
    load(0, kr, vr);

    for (int t = 0; t < ntiles; t++) {
        const int kv0 = t * 64;
        __syncthreads();                     // all waves done reading previous tile
        store(kr, vr);
        __syncthreads();                     // tile visible (LDS drain only)
        if (t + 1 < ntiles) load(t + 1, kr, vr);   // AFTER barrier: hides under compute below

        // ---- S = Q K^T (pre-scaled) ----
        bf16x8 bk[4][2];
        #pragma unroll
        for (int ct = 0; ct < 4; ct++)
            #pragma unroll
            for (int ks = 0; ks < 2; ks++) {
                int row = ct * 16 + lr;
                bk[ct][ks] = *reinterpret_cast<const bf16x8*>(klds + swz(row, row * 128 + ks * 64 + lk * 16));
            }
        f32x4 s[4];
        #pragma unroll
        for (int ct = 0; ct < 4; ct++) {
            f32x4 a = {0.f, 0.f, 0.f, 0.f};
            a = __builtin_amdgcn_mfma_f32_16x16x32_bf16(aq[0], bk[ct][0], a, 0, 0, 0);
            a = __builtin_amdgcn_mfma_f32_16x16x32_bf16(aq[1], bk[ct][1], a, 0, 0, 0);
            s[ct] = a;
        }

        // ---- causal mask + online softmax (DPP reduces; raw v_exp_f32) ----
        const bool needmask = (kv0 + 63) > qrow;
        float mx[4] = {-INFINITY, -INFINITY, -INFINITY, -INFINITY};
        #pragma unroll
        for (int ct = 0; ct < 4; ct++) {
            #pragma unroll
            for (int j = 0; j < 4; j++) {
                float v = s[ct][j];
                if (needmask) {
                    int row = qrow + lk * 4 + j;
                    int col = kv0 + ct * 16 + lr;
                    if (col > row) v = -INFINITY;
                }
                s[ct][j] = v;
                mx[j] = fmaxf(mx[j], v);
            }
        }
        #pragma unroll
        for (int j = 0; j < 4; j++) {
            mx[j] = redmax16(mx[j]);
            float mnew = fmaxf(m_i[j], mx[j]);
            float corr = __builtin_amdgcn_exp2f(m_i[j] - mnew);
            m_i[j] = mnew;
            l_i[j] *= corr;
            #pragma unroll
            for (int dt = 0; dt < 4; dt++) o[dt][j] *= corr;
        }
        float rs[4] = {0.f, 0.f, 0.f, 0.f};
        #pragma unroll
        for (int ct = 0; ct < 4; ct++) {
            #pragma unroll
            for (int j = 0; j < 4; j++) {
                float p = __builtin_amdgcn_exp2f(s[ct][j] - m_i[j]);
                rs[j] += p;
                *reinterpret_cast<unsigned short*>(&plds[w][0] + (lk * 4 + j) * 144 + (ct * 16 + lr) * 2) = f2bf_fast(p);
            }
        }
        #pragma unroll
        for (int j = 0; j < 4; j++) l_i[j] += redsum16(rs[j]);

        __threadfence_block();   // per-wave P write->read ordering

        // ---- O += P V ----
        bf16x8 pa[2];
        #pragma unroll
        for (int ks = 0; ks < 2; ks++)
            pa[ks] = *reinterpret_cast<const bf16x8*>(&plds[w][0] + lr * 144 + ks * 64 + lk * 16);
        bf16x8 vbf[4][2];
        #pragma unroll
        for (int dt = 0; dt < 4; dt++)
            #pragma unroll
            for (int ks = 0; ks < 2; ks++) {
                int row = dt * 16 + lr;
                vbf[dt][ks] = *reinterpret_cast<const bf16x8*>(vlds + swz(row, row * 128 + ks * 64 + lk * 16));
            }
        #pragma unroll
        for (int dt = 0; dt < 4; dt++)
            #pragma unroll
            for (int ks = 0; ks < 2; ks++)
                o[dt] = __builtin_amdgcn_mfma_f32_16x16x32_bf16(pa[ks], vbf[dt][ks], o[dt], 0, 0, 0);
    }

    // ---- epilogue: normalize + store ctx (bf16) ----
    #pragma unroll
    for (int j = 0; j < 4; j++) {
        float inv = 1.0f / l_i[j];
        int row = qrow + lk * 4 + j;
        #pragma unroll
        for (int dt = 0; dt < 4; dt++)
            Ctx[headoff + (size_t)row * D_MODEL + dt * 16 + lr] = f2bf(o[dt][j] * inv);
    }
}

extern "C" void kernel_launch(void* const* d_in, const int* in_sizes, int n_in,
                              void* d_out, int out_size, void* d_ws, size_t ws_size,
                              hipStream_t stream)
{
    const float* x   = (const float*)d_in[0];
    const float* w_q = (const float*)d_in[2];
    const float* b_q = (const float*)d_in[3];
    const float* w_k = (const float*)d_in[4];
    const float* b_k = (const float*)d_in[5];
    const float* w_v = (const float*)d_in[6];
    const float* b_v = (const float*)d_in[7];
    const float* w_o = (const float*)d_in[8];
    const float* b_o = (const float*)d_in[9];

    const size_t SEG = (size_t)MROWS * D_MODEL;        // 4M elems
    const size_t WSEG = (size_t)D_MODEL * D_MODEL;     // 1M elems
    unsigned short* Qb  = (unsigned short*)d_ws;
    unsigned short* Kb  = Qb + SEG;
    unsigned short* Vt  = Kb + SEG;                    // [1024][4096] (transposed)
    unsigned short* Xb  = Vt + SEG;                    // x bf16; later reused as Ctx
    unsigned short* Ctx = Xb;                          // alias: attn overwrites after x consumed
    unsigned short* Wqb = Xb + SEG;
    unsigned short* Wkb = Wqb + WSEG;
    unsigned short* Wvb = Wkb + WSEG;
    unsigned short* Wob = Wvb + WSEG;
    const bool fullws = ws_size >= (4 * SEG + 4 * WSEG) * 2;   // 40 MB

    const float QSC = 0.125f * 1.44269504088896f;  // 1/sqrt(dk) * log2(e), folded into Q

    dim3 blk(256);
    dim3 qkvgrid(D_MODEL / 128, MROWS / 128, 3);   // (8, 32, 3)
    dim3 ogrid(D_MODEL / 128, MROWS / 128);        // (8, 32)
    dim3 agrid(SEQ / 64, 32);                      // (32, 32)

    hipLaunchKernelGGL(cvt_bf16, dim3(4096), blk, 0, stream, x, Xb, (int)(SEG / 4));
    if (fullws) {
        hipLaunchKernelGGL(cvt_w4, dim3(1024, 1, 4), blk, 0, stream,
                           w_q, w_k, w_v, w_o, Wqb, Wkb, Wvb, Wob, (int)(WSEG / 4));
        hipLaunchKernelGGL((gemm_qkv<true>), qkvgrid, blk, 0, stream, Xb,
                           (const void*)Wqb, (const void*)Wkb, (const void*)Wvb,
                           b_q, b_k, b_v, (void*)Qb, (void*)Kb, (void*)Vt, QSC);
        hipLaunchKernelGGL(attn_fwd, agrid, blk, 0, stream, Qb, Kb, Vt, Ctx);
        hipLaunchKernelGGL((gemm_o<true>), ogrid, blk, 0, stream, Ctx, (const void*)Wob, b_o, d_out);
    } else {
        hipLaunchKernelGGL((gemm_qkv<false>), qkvgrid, blk, 0, stream, Xb,
                           (const void*)w_q, (const void*)w_k, (const void*)w_v,
                           b_q, b_k, b_v, (void*)Qb, (void*)Kb, (void*)Vt, QSC);
        hipLaunchKernelGGL(attn_fwd, agrid, blk, 0, stream, Qb, Kb, Vt, Ctx);
        hipLaunchKernelGGL((gemm_o<false>), ogrid, blk, 0, stream, Ctx, (const void*)w_o, b_o, d_out);
    }
}

// Round 9
// 327.350 us; speedup vs baseline: 1.2751x; 1.0002x over previous
//
#include <hip/hip_runtime.h>

// MHA forward: B=2, S=2048, D=1024, H=16, dk=64.
// Pipeline: cvt x,W -> bf16; fused QKV GEMM (V transposed out) -> flash attn -> O GEMM.
// ws layout (bf16 elems): Qb[4M] Kb[4M] Vt[4M] Xb/Ctx[4M] (+Wb[4x1M] if ws >= 40MB).
// R9 change: __threadfence_block (emits s_waitcnt vmcnt(0) -> drained the KV prefetch
// mid-tile, every tile) replaced by a precise LDS-only s_waitcnt lgkmcnt(0).

#define D_MODEL 1024
#define SEQ     2048
#define NHEAD   16
#define DKH     64
#define MROWS   4096   // B*S

typedef __attribute__((ext_vector_type(8))) short bf16x8;
typedef __attribute__((ext_vector_type(4))) float f32x4;

__device__ __forceinline__ unsigned short f2bf(float f) {
    union { float f; unsigned u; } v; v.f = f;
    unsigned r = (v.u + 0x7fffu + ((v.u >> 16) & 1u)) >> 16;   // RNE
    return (unsigned short)r;
}
__device__ __forceinline__ unsigned short f2bf_fast(float f) {  // round-half-up (P in [0,1])
    union { float f; unsigned u; } v; v.f = f;
    return (unsigned short)((v.u + 0x8000u) >> 16);
}
__device__ __forceinline__ unsigned long long pack4(float4 v) {
    return (unsigned long long)f2bf(v.x)
         | ((unsigned long long)f2bf(v.y) << 16)
         | ((unsigned long long)f2bf(v.z) << 32)
         | ((unsigned long long)f2bf(v.w) << 48);
}

// XOR swizzle: spreads 128B-stride rows across banks; preserves 16B alignment.
__device__ __forceinline__ int swz(int row, int byte) { return byte ^ ((row & 7) << 4); }

// DPP 16-lane butterfly reduce (reduce group = one DPP row of 16 lanes).
#define DPP_F(x, ctrl) __builtin_bit_cast(float, __builtin_amdgcn_mov_dpp(__builtin_bit_cast(int, (x)), (ctrl), 0xf, 0xf, true))
__device__ __forceinline__ float redmax16(float x) {
    x = fmaxf(x, DPP_F(x, 0xB1));
    x = fmaxf(x, DPP_F(x, 0x4E));
    x = fmaxf(x, DPP_F(x, 0x141));
    x = fmaxf(x, DPP_F(x, 0x140));
    return x;
}
__device__ __forceinline__ float redsum16(float x) {
    x += DPP_F(x, 0xB1);
    x += DPP_F(x, 0x4E);
    x += DPP_F(x, 0x141);
    x += DPP_F(x, 0x140);
    return x;
}

// ---------------------------------------------------------------------------
// fp32 -> bf16 bulk converts
// ---------------------------------------------------------------------------
__global__ __launch_bounds__(256) void cvt_bf16(const float* __restrict__ src,
                                                unsigned short* __restrict__ dst, int n4)
{
    int i = blockIdx.x * 256 + threadIdx.x;
    if (i < n4) {
        float4 v = reinterpret_cast<const float4*>(src)[i];
        reinterpret_cast<unsigned long long*>(dst)[i] = pack4(v);
    }
}
__global__ __launch_bounds__(256) void cvt_w4(const float* s0, const float* s1,
                                              const float* s2, const float* s3,
                                              unsigned short* d0, unsigned short* d1,
                                              unsigned short* d2, unsigned short* d3, int n4)
{
    const float* s = (blockIdx.z == 0) ? s0 : (blockIdx.z == 1) ? s1 : (blockIdx.z == 2) ? s2 : s3;
    unsigned short* d = (blockIdx.z == 0) ? d0 : (blockIdx.z == 1) ? d1 : (blockIdx.z == 2) ? d2 : d3;
    int i = blockIdx.x * 256 + threadIdx.x;
    if (i < n4) {
        float4 v = reinterpret_cast<const float4*>(s)[i];
        reinterpret_cast<unsigned long long*>(d)[i] = pack4(v);
    }
}

// ---------------------------------------------------------------------------
// Shared GEMM body: C[128x128 tile] = (A @ W^T + bias) * oscale, K = 1024.
// Pipeline: sync; storeLDS; sync; issue next loads; compute.
// ---------------------------------------------------------------------------
template<bool W_BF16>
__device__ __forceinline__ void gemm_body(const unsigned short* __restrict__ Ap,
                                          const void* __restrict__ Wp,
                                          const float* __restrict__ bias,
                                          void* __restrict__ Cp, float oscale,
                                          bool outT, bool outBF16,
                                          int m0, int n0, unsigned char* lds)
{
    const int tid = threadIdx.x;
    const int w = tid >> 6, l = tid & 63;
    const int wm = (w >> 1) * 64, wn = (w & 1) * 64;
    const int lr = l & 15, lk = l >> 4;

    f32x4 acc[4][4] = {};
    int4 ra[4], rwb[4];
    float4 rwf[8];

    auto loadA = [&](int k0) {
        #pragma unroll
        for (int i = 0; i < 4; i++) {
            int c = tid + i * 256;
            int row = c >> 3, col8 = c & 7;
            ra[i] = *reinterpret_cast<const int4*>(Ap + (size_t)(m0 + row) * D_MODEL + k0 + col8 * 8);
        }
    };
    auto loadW = [&](int k0) {
        if constexpr (W_BF16) {
            const unsigned short* W = (const unsigned short*)Wp;
            #pragma unroll
            for (int i = 0; i < 4; i++) {
                int c = tid + i * 256;
                int row = c >> 3, col8 = c & 7;
                rwb[i] = *reinterpret_cast<const int4*>(W + (size_t)(n0 + row) * D_MODEL + k0 + col8 * 8);
            }
        } else {
            const float* W = (const float*)Wp;
            #pragma unroll
            for (int i = 0; i < 8; i++) {
                int c = tid + i * 256;
                int row = c >> 4, col4 = c & 15;
                rwf[i] = *reinterpret_cast<const float4*>(W + (size_t)(n0 + row) * D_MODEL + k0 + col4 * 4);
            }
        }
    };
    auto storeT = [&]() {
        #pragma unroll
        for (int i = 0; i < 4; i++) {
            int c = tid + i * 256;
            int row = c >> 3, col8 = c & 7;
            *reinterpret_cast<int4*>(lds + swz(row, row * 128 + col8 * 16)) = ra[i];
        }
        if constexpr (W_BF16) {
            #pragma unroll
            for (int i = 0; i < 4; i++) {
                int c = tid + i * 256;
                int row = c >> 3, col8 = c & 7;
                *reinterpret_cast<int4*>(lds + 16384 + swz(row, row * 128 + col8 * 16)) = rwb[i];
            }
        } else {
            #pragma unroll
            for (int i = 0; i < 8; i++) {
                int c = tid + i * 256;
                int row = c >> 4, col4 = c & 15;
                *reinterpret_cast<unsigned long long*>(lds + 16384 + swz(row, row * 128 + col4 * 8)) = pack4(rwf[i]);
            }
        }
    };

    loadA(0); loadW(0);
    for (int k0 = 0; k0 < D_MODEL; k0 += 64) {
        __syncthreads();
        storeT();
        __syncthreads();
        if (k0 + 64 < D_MODEL) { loadA(k0 + 64); loadW(k0 + 64); }  // latency hides under compute
        #pragma unroll
        for (int ks = 0; ks < 2; ks++) {
            bf16x8 af[4], bfr[4];
            #pragma unroll
            for (int rt = 0; rt < 4; rt++) {
                int row = wm + rt * 16 + lr;
                af[rt] = *reinterpret_cast<const bf16x8*>(lds + swz(row, row * 128 + ks * 64 + lk * 16));
            }
            #pragma unroll
            for (int ct = 0; ct < 4; ct++) {
                int row = wn + ct * 16 + lr;
                bfr[ct] = *reinterpret_cast<const bf16x8*>(lds + 16384 + swz(row, row * 128 + ks * 64 + lk * 16));
            }
            #pragma unroll
            for (int rt = 0; rt < 4; rt++)
                #pragma unroll
                for (int ct = 0; ct < 4; ct++)
                    acc[rt][ct] = __builtin_amdgcn_mfma_f32_16x16x32_bf16(af[rt], bfr[ct], acc[rt][ct], 0, 0, 0);
        }
    }
    #pragma unroll
    for (int ct = 0; ct < 4; ct++) {
        int n = n0 + wn + ct * 16 + lr;
        float bv = bias[n];
        #pragma unroll
        for (int rt = 0; rt < 4; rt++) {
            #pragma unroll
            for (int j = 0; j < 4; j++) {
                int m = m0 + wm + rt * 16 + lk * 4 + j;
                float v = (acc[rt][ct][j] + bv) * oscale;
                if (outT)
                    ((unsigned short*)Cp)[(size_t)n * MROWS + m] = f2bf(v);
                else if (outBF16)
                    ((unsigned short*)Cp)[(size_t)m * D_MODEL + n] = f2bf(v);
                else
                    ((float*)Cp)[(size_t)m * D_MODEL + n] = v;
            }
        }
    }
}

// Fused QKV GEMM: blockIdx.z in {0,1,2} -> (Q, K, V^T). 3x blocks/CU vs serial.
template<bool W_BF16>
__global__ __launch_bounds__(256) void gemm_qkv(const unsigned short* __restrict__ Xb,
                                                const void* W0, const void* W1, const void* W2,
                                                const float* b0, const float* b1, const float* b2,
                                                void* C0, void* C1, void* C2, float qsc)
{
    __shared__ __align__(16) unsigned char lds[32768];
    const int z = blockIdx.z;
    const void* W = (z == 0) ? W0 : (z == 1) ? W1 : W2;
    const float* bias = (z == 0) ? b0 : (z == 1) ? b1 : b2;
    void* C = (z == 0) ? C0 : (z == 1) ? C1 : C2;
    gemm_body<W_BF16>(Xb, W, bias, C, (z == 0) ? qsc : 1.0f, z == 2, true,
                      blockIdx.y * 128, blockIdx.x * 128, lds);
}

// Single GEMM (output projection): fp32 out.
template<bool W_BF16>
__global__ __launch_bounds__(256) void gemm_o(const unsigned short* __restrict__ Ap,
                                              const void* __restrict__ Wp,
                                              const float* __restrict__ bias,
                                              void* __restrict__ Cp)
{
    __shared__ __align__(16) unsigned char lds[32768];
    gemm_body<W_BF16>(Ap, Wp, bias, Cp, 1.0f, false, false,
                      blockIdx.y * 128, blockIdx.x * 128, lds);
}

// ---------------------------------------------------------------------------
// Causal flash attention. Grid: (S/64, B*H). 4 waves; wave owns 16 Q-rows.
// KV tile = 64 staged via regs -> swizzled LDS; prefetch issued after barrier 2.
// P write->read ordering: same-wave DS ops are in-order at the LDS; the inline
// lgkmcnt(0) (NOT __threadfence_block, which drains vmcnt too) just pins the
// compiler's memory order without draining the KV prefetch.
// ---------------------------------------------------------------------------
__global__ __launch_bounds__(256) void attn_fwd(const unsigned short* __restrict__ Qb,
                                                const unsigned short* __restrict__ Kb,
                                                const unsigned short* __restrict__ Vt,
                                                unsigned short* __restrict__ Ctx)
{
    __shared__ __align__(16) unsigned char klds[8192];        // K tile [64][64] bf16
    __shared__ __align__(16) unsigned char vlds[8192];        // V^T tile [64][64] bf16
    __shared__ __align__(16) unsigned char plds[4][16 * 144]; // per-wave P [16][64+8pad]

    const int tid = threadIdx.x, w = tid >> 6, l = tid & 63;
    const int lr = l & 15, lk = l >> 4;
    const int q0 = ((int)gridDim.x - 1 - (int)blockIdx.x) * 64;   // big blocks first
    const int b = blockIdx.y >> 4, h = blockIdx.y & 15;
    const size_t headoff = (size_t)b * SEQ * D_MODEL + (size_t)h * DKH;   // Q/K/Ctx
    const size_t vtoff   = (size_t)h * DKH * MROWS + (size_t)b * SEQ;     // Vt[h*64+d][b*2048+kv]
    const int qrow = q0 + w * 16;

    // Q fragments (held for the whole kernel; Q pre-scaled by 0.125*log2e)
    bf16x8 aq[2];
    #pragma unroll
    for (int ks = 0; ks < 2; ks++)
        aq[ks] = *reinterpret_cast<const bf16x8*>(
            Qb + headoff + (size_t)(qrow + lr) * D_MODEL + ks * 32 + lk * 8);

    f32x4 o[4] = {};
    float m_i[4], l_i[4];
    #pragma unroll
    for (int j = 0; j < 4; j++) { m_i[j] = -INFINITY; l_i[j] = 0.f; }

    const int row_s = tid >> 3, col8 = tid & 7;
    auto load = [&](int t, int4* kr, int4* vr) {
        const int kv0 = t * 64;
        #pragma unroll
        for (int i = 0; i < 2; i++) {
            int row = row_s + i * 32;
            kr[i] = *reinterpret_cast<const int4*>(Kb + headoff + (size_t)(kv0 + row) * D_MODEL + col8 * 8);
            vr[i] = *reinterpret_cast<const int4*>(Vt + vtoff + (size_t)row * MROWS + kv0 + col8 * 8);
        }
    };
    auto store = [&](const int4* kr, const int4* vr) {
        #pragma unroll
        for (int i = 0; i < 2; i++) {
            int row = row_s + i * 32;
            *reinterpret_cast<int4*>(klds + swz(row, row * 128 + col8 * 16)) = kr[i];
            *reinterpret_cast<int4*>(vlds + swz(row, row * 128 + col8 * 16)) = vr[i];
        }
    };

    const int ntiles = q0 / 64 + 1;
    int4 kr[2], vr[2];
    load(0, kr, vr);

    for (int t = 0; t < ntiles; t++) {
        const int kv0 = t * 64;
        __syncthreads();                     // all waves done reading previous tile
        store(kr, vr);
        __syncthreads();                     // tile visible
        if (t + 1 < ntiles) load(t + 1, kr, vr);   // hides under compute below

        // ---- S = Q K^T (pre-scaled) ----
        bf16x8 bk[4][2];
        #pragma unroll
        for (int ct = 0; ct < 4; ct++)
            #pragma unroll
            for (int ks = 0; ks < 2; ks++) {
                int row = ct * 16 + lr;
                bk[ct][ks] = *reinterpret_cast<const bf16x8*>(klds + swz(row, row * 128 + ks * 64 + lk * 16));
            }
        f32x4 s[4];
        #pragma unroll
        for (int ct = 0; ct < 4; ct++) {
            f32x4 a = {0.f, 0.f, 0.f, 0.f};
            a = __builtin_amdgcn_mfma_f32_16x16x32_bf16(aq[0], bk[ct][0], a, 0, 0, 0);
            a = __builtin_amdgcn_mfma_f32_16x16x32_bf16(aq[1], bk[ct][1], a, 0, 0, 0);
            s[ct] = a;
        }

        // ---- causal mask + online softmax (DPP reduces; raw v_exp_f32) ----
        const bool needmask = (kv0 + 63) > qrow;
        float mx[4] = {-INFINITY, -INFINITY, -INFINITY, -INFINITY};
        #pragma unroll
        for (int ct = 0; ct < 4; ct++) {
            #pragma unroll
            for (int j = 0; j < 4; j++) {
                float v = s[ct][j];
                if (needmask) {
                    int row = qrow + lk * 4 + j;
                    int col = kv0 + ct * 16 + lr;
                    if (col > row) v = -INFINITY;
                }
                s[ct][j] = v;
                mx[j] = fmaxf(mx[j], v);
            }
        }
        #pragma unroll
        for (int j = 0; j < 4; j++) {
            mx[j] = redmax16(mx[j]);
            float mnew = fmaxf(m_i[j], mx[j]);
            float corr = __builtin_amdgcn_exp2f(m_i[j] - mnew);
            m_i[j] = mnew;
            l_i[j] *= corr;
            #pragma unroll
            for (int dt = 0; dt < 4; dt++) o[dt][j] *= corr;
        }
        float rs[4] = {0.f, 0.f, 0.f, 0.f};
        #pragma unroll
        for (int ct = 0; ct < 4; ct++) {
            #pragma unroll
            for (int j = 0; j < 4; j++) {
                float p = __builtin_amdgcn_exp2f(s[ct][j] - m_i[j]);
                rs[j] += p;
                *reinterpret_cast<unsigned short*>(&plds[w][0] + (lk * 4 + j) * 144 + (ct * 16 + lr) * 2) = f2bf_fast(p);
            }
        }
        #pragma unroll
        for (int j = 0; j < 4; j++) l_i[j] += redsum16(rs[j]);

        // P write->read: same-wave DS ops are in-order; LDS-only wait, no vmcnt drain
        asm volatile("s_waitcnt lgkmcnt(0)" ::: "memory");

        // ---- O += P V ----
        bf16x8 pa[2];
        #pragma unroll
        for (int ks = 0; ks < 2; ks++)
            pa[ks] = *reinterpret_cast<const bf16x8*>(&plds[w][0] + lr * 144 + ks * 64 + lk * 16);
        bf16x8 vbf[4][2];
        #pragma unroll
        for (int dt = 0; dt < 4; dt++)
            #pragma unroll
            for (int ks = 0; ks < 2; ks++) {
                int row = dt * 16 + lr;
                vbf[dt][ks] = *reinterpret_cast<const bf16x8*>(vlds + swz(row, row * 128 + ks * 64 + lk * 16));
            }
        #pragma unroll
        for (int dt = 0; dt < 4; dt++)
            #pragma unroll
            for (int ks = 0; ks < 2; ks++)
                o[dt] = __builtin_amdgcn_mfma_f32_16x16x32_bf16(pa[ks], vbf[dt][ks], o[dt], 0, 0, 0);
    }

    // ---- epilogue: normalize + store ctx (bf16) ----
    #pragma unroll
    for (int j = 0; j < 4; j++) {
        float inv = 1.0f / l_i[j];
        int row = qrow + lk * 4 + j;
        #pragma unroll
        for (int dt = 0; dt < 4; dt++)
            Ctx[headoff + (size_t)row * D_MODEL + dt * 16 + lr] = f2bf(o[dt][j] * inv);
    }
}

extern "C" void kernel_launch(void* const* d_in, const int* in_sizes, int n_in,
                              void* d_out, int out_size, void* d_ws, size_t ws_size,
                              hipStream_t stream)
{
    const float* x   = (const float*)d_in[0];
    const float* w_q = (const float*)d_in[2];
    const float* b_q = (const float*)d_in[3];
    const float* w_k = (const float*)d_in[4];
    const float* b_k = (const float*)d_in[5];
    const float* w_v = (const float*)d_in[6];
    const float* b_v = (const float*)d_in[7];
    const float* w_o = (const float*)d_in[8];
    const float* b_o = (const float*)d_in[9];

    const size_t SEG = (size_t)MROWS * D_MODEL;        // 4M elems
    const size_t WSEG = (size_t)D_MODEL * D_MODEL;     // 1M elems
    unsigned short* Qb  = (unsigned short*)d_ws;
    unsigned short* Kb  = Qb + SEG;
    unsigned short* Vt  = Kb + SEG;                    // [1024][4096] (transposed)
    unsigned short* Xb  = Vt + SEG;                    // x bf16; later reused as Ctx
    unsigned short* Ctx = Xb;                          // alias: attn overwrites after x consumed
    unsigned short* Wqb = Xb + SEG;
    unsigned short* Wkb = Wqb + WSEG;
    unsigned short* Wvb = Wkb + WSEG;
    unsigned short* Wob = Wvb + WSEG;
    const bool fullws = ws_size >= (4 * SEG + 4 * WSEG) * 2;   // 40 MB

    const float QSC = 0.125f * 1.44269504088896f;  // 1/sqrt(dk) * log2(e), folded into Q

    dim3 blk(256);
    dim3 qkvgrid(D_MODEL / 128, MROWS / 128, 3);   // (8, 32, 3)
    dim3 ogrid(D_MODEL / 128, MROWS / 128);        // (8, 32)
    dim3 agrid(SEQ / 64, 32);                      // (32, 32)

    hipLaunchKernelGGL(cvt_bf16, dim3(4096), blk, 0, stream, x, Xb, (int)(SEG / 4));
    if (fullws) {
        hipLaunchKernelGGL(cvt_w4, dim3(1024, 1, 4), blk, 0, stream,
                           w_q, w_k, w_v, w_o, Wqb, Wkb, Wvb, Wob, (int)(WSEG / 4));
        hipLaunchKernelGGL((gemm_qkv<true>), qkvgrid, blk, 0, stream, Xb,
                           (const void*)Wqb, (const void*)Wkb, (const void*)Wvb,
                           b_q, b_k, b_v, (void*)Qb, (void*)Kb, (void*)Vt, QSC);
        hipLaunchKernelGGL(attn_fwd, agrid, blk, 0, stream, Qb, Kb, Vt, Ctx);
        hipLaunchKernelGGL((gemm_o<true>), ogrid, blk, 0, stream, Ctx, (const void*)Wob, b_o, d_out);
    } else {
        hipLaunchKernelGGL((gemm_qkv<false>), qkvgrid, blk, 0, stream, Xb,
                           (const void*)w_q, (const void*)w_k, (const void*)w_v,
                           b_q, b_k, b_v, (void*)Qb, (void*)Kb, (void*)Vt, QSC);
        hipLaunchKernelGGL(attn_fwd, agrid, blk, 0, stream, Qb, Kb, Vt, Ctx);
        hipLaunchKernelGGL((gemm_o<false>), ogrid, blk, 0, stream, Ctx, (const void*)w_o, b_o, d_out);
    }
}